// Round 4
// baseline (94.579 us; speedup 1.0000x reference)
//
#include <hip/hip_runtime.h>
#include <math.h>

typedef float f32x4 __attribute__((ext_vector_type(4)));

// ---------------------------------------------------------------------------
// Kernel 1: per-camera precompute. cams[c*16] = {R[9], t[3], pad[4]}
// 64 B per camera -> every gather touches exactly one 64B-aligned line.
// ---------------------------------------------------------------------------
__global__ void cam_precompute(const float* __restrict__ params,
                               float* __restrict__ cams, int size) {
    int c = blockIdx.x * blockDim.x + threadIdx.x;
    if (c >= size) return;
    float a  = params[6 * c + 0];
    float b  = params[6 * c + 1];
    float cc = params[6 * c + 2];
    float t2 = a * a + b * b + cc * cc;
    float t  = sqrtf(t2);
    float sin_c, cos_c;
    if (t < 1e-8f) {
        sin_c = 1.0f;
        cos_c = 0.5f;
    } else {
        sin_c = sinf(t) / t;
        cos_c = (1.0f - cosf(t)) / t2;
    }
    float sa = sin_c * a, sb = sin_c * b, sc = sin_c * cc;
    float cab = cos_c * a * b, cac = cos_c * a * cc, cbc = cos_c * b * cc;

    float* o = cams + 16 * c;
    // R = I + sin_c*K + cos_c*K*K,  K = [[0,a,b],[-a,0,c],[-b,-c,0]]
    o[0] = 1.0f - cos_c * (a * a + b * b);
    o[1] =  sa - cbc;
    o[2] =  sb + cac;
    o[3] = -sa - cbc;
    o[4] = 1.0f - cos_c * (a * a + cc * cc);
    o[5] =  sc - cab;
    o[6] = -sb + cac;
    o[7] = -sc - cab;
    o[8] = 1.0f - cos_c * (b * b + cc * cc);
    o[9]  = params[6 * c + 3];
    o[10] = params[6 * c + 4];
    o[11] = params[6 * c + 5];
}

// ---------------------------------------------------------------------------
// Kernel 2: 1024-point tile per 256-thread block. All global traffic is
// lane-contiguous; LDS is the transpose arena. NEW vs R3: idx loads, o/d
// staging loads AND the 12 camera-gather loads all issue BEFORE the first
// barrier, so gather latency hides under staging instead of stalling
// phase 2 (barrier is a compiler memory fence -- no auto-hoist).
// out layout (floats): [new_o: 3N][new_d: 3N][trans: 3N][R: 9N]
// ---------------------------------------------------------------------------
__launch_bounds__(256, 4)
__global__ void cam_apply(const int* __restrict__ idx,
                          const float* __restrict__ of,
                          const float* __restrict__ df,
                          const f32x4* __restrict__ cams4,
                          float* __restrict__ out,
                          long long N) {
    __shared__ float lds[9216];   // 36 KB arena -> 4 blocks/CU
    const int tid = threadIdx.x;
    const long long tileBase = (long long)blockIdx.x * 1024;

    if (tileBase + 1024 <= N) {
        // ---- P0: issue ALL global loads up front ----
        int id[4];
#pragma unroll
        for (int k = 0; k < 4; ++k) id[k] = idx[tileBase + tid + 256 * k];

        const f32x4* o4 = (const f32x4*)(of + 3 * tileBase);   // 768 f32x4
        const f32x4* d4 = (const f32x4*)(df + 3 * tileBase);
        f32x4 so[3], sd[3];
#pragma unroll
        for (int j = 0; j < 3; ++j) { so[j] = o4[tid + 256 * j];
                                      sd[j] = d4[tid + 256 * j]; }

        f32x4 c0[4], c1[4], c2[4];
#pragma unroll
        for (int k = 0; k < 4; ++k) {
            const f32x4* cp = cams4 + 4 * (long long)id[k];
            c0[k] = cp[0]; c1[k] = cp[1]; c2[k] = cp[2];
        }

        // ---- P1: stage o, d tiles into LDS (dense) ----
        f32x4* A = (f32x4*)lds;              // o tile: floats [0, 3072)
        f32x4* B = (f32x4*)(lds + 3072);     // d tile: floats [3072, 6144)
#pragma unroll
        for (int j = 0; j < 3; ++j) { A[tid + 256 * j] = so[j];
                                      B[tid + 256 * j] = sd[j]; }
        __syncthreads();

        // ---- P2: compute 4 points/thread (n = tid + 256k), pure LDS+VALU ----
        float no[12], nd[12];
#pragma unroll
        for (int k = 0; k < 4; ++k) {
            int n = tid + 256 * k;
            float ox = lds[3 * n + 0], oy = lds[3 * n + 1], oz = lds[3 * n + 2];
            float dx = lds[3072 + 3 * n + 0], dy = lds[3072 + 3 * n + 1],
                  dz = lds[3072 + 3 * n + 2];

            no[3 * k + 0] = c0[k][0] * ox + c0[k][1] * oy + c0[k][2] * oz + c2[k][1];
            no[3 * k + 1] = c0[k][3] * ox + c1[k][0] * oy + c1[k][1] * oz + c2[k][2];
            no[3 * k + 2] = c1[k][2] * ox + c1[k][3] * oy + c2[k][0] * oz + c2[k][3];

            nd[3 * k + 0] = c0[k][0] * dx + c0[k][1] * dy + c0[k][2] * dz;
            nd[3 * k + 1] = c0[k][3] * dx + c1[k][0] * dy + c1[k][1] * dz;
            nd[3 * k + 2] = c1[k][2] * dx + c1[k][3] * dy + c2[k][0] * dz;
        }
        __syncthreads();   // all o/d reads done; arena reusable

        // ---- P3: write no/nd/tr to arena (stride-3, coprime 32 -> clean) ----
#pragma unroll
        for (int k = 0; k < 4; ++k) {
            int n = tid + 256 * k;
            lds[3 * n + 0] = no[3 * k + 0];
            lds[3 * n + 1] = no[3 * k + 1];
            lds[3 * n + 2] = no[3 * k + 2];
            lds[3072 + 3 * n + 0] = nd[3 * k + 0];
            lds[3072 + 3 * n + 1] = nd[3 * k + 1];
            lds[3072 + 3 * n + 2] = nd[3 * k + 2];
            lds[6144 + 3 * n + 0] = c2[k][1];
            lds[6144 + 3 * n + 1] = c2[k][2];
            lds[6144 + 3 * n + 2] = c2[k][3];
        }
        __syncthreads();

        // ---- P4: dense flush of new_o, new_d, trans ----
        const f32x4* src = (const f32x4*)lds;
        f32x4* g0 = (f32x4*)(out + 3 * tileBase);
        f32x4* g1 = (f32x4*)(out + 3 * N + 3 * tileBase);
        f32x4* g2 = (f32x4*)(out + 6 * N + 3 * tileBase);
#pragma unroll
        for (int j = 0; j < 3; ++j) g0[tid + 256 * j] = src[tid + 256 * j];
#pragma unroll
        for (int j = 0; j < 3; ++j) g1[tid + 256 * j] = src[768 + tid + 256 * j];
#pragma unroll
        for (int j = 0; j < 3; ++j) g2[tid + 256 * j] = src[1536 + tid + 256 * j];
        __syncthreads();   // flush reads done; arena reusable

        // ---- P5: R tile (9216 floats = whole arena), stride-9 (coprime 32) ----
#pragma unroll
        for (int k = 0; k < 4; ++k) {
            int n = tid + 256 * k;
            lds[9 * n + 0] = c0[k][0];
            lds[9 * n + 1] = c0[k][1];
            lds[9 * n + 2] = c0[k][2];
            lds[9 * n + 3] = c0[k][3];
            lds[9 * n + 4] = c1[k][0];
            lds[9 * n + 5] = c1[k][1];
            lds[9 * n + 6] = c1[k][2];
            lds[9 * n + 7] = c1[k][3];
            lds[9 * n + 8] = c2[k][0];
        }
        __syncthreads();

        f32x4* g3 = (f32x4*)(out + 9 * N + 9 * tileBase);
#pragma unroll
        for (int j = 0; j < 9; ++j) g3[tid + 256 * j] = src[tid + 256 * j];
    } else {
        // ---- tail tile: scalar guarded path ----
        for (int k = 0; k < 4; ++k) {
            long long n = tileBase + tid + 256 * k;
            if (n >= N) continue;
            int cid = idx[n];
            const f32x4* cp = cams4 + 4 * (long long)cid;
            f32x4 c0 = cp[0], c1 = cp[1], c2 = cp[2];
            float ox = of[3 * n + 0], oy = of[3 * n + 1], oz = of[3 * n + 2];
            float dx = df[3 * n + 0], dy = df[3 * n + 1], dz = df[3 * n + 2];

            out[3 * n + 0] = c0[0] * ox + c0[1] * oy + c0[2] * oz + c2[1];
            out[3 * n + 1] = c0[3] * ox + c1[0] * oy + c1[1] * oz + c2[2];
            out[3 * n + 2] = c1[2] * ox + c1[3] * oy + c2[0] * oz + c2[3];

            out[3 * N + 3 * n + 0] = c0[0] * dx + c0[1] * dy + c0[2] * dz;
            out[3 * N + 3 * n + 1] = c0[3] * dx + c1[0] * dy + c1[1] * dz;
            out[3 * N + 3 * n + 2] = c1[2] * dx + c1[3] * dy + c2[0] * dz;

            out[6 * N + 3 * n + 0] = c2[1];
            out[6 * N + 3 * n + 1] = c2[2];
            out[6 * N + 3 * n + 2] = c2[3];

            float Rv[9] = {c0[0], c0[1], c0[2], c0[3], c1[0], c1[1],
                           c1[2], c1[3], c2[0]};
            for (int j = 0; j < 9; ++j) out[9 * N + 9 * n + j] = Rv[j];
        }
    }
}

extern "C" void kernel_launch(void* const* d_in, const int* in_sizes, int n_in,
                              void* d_out, int out_size, void* d_ws, size_t ws_size,
                              hipStream_t stream) {
    const float* params = (const float*)d_in[0];
    const int*   idx    = (const int*)d_in[1];
    const float* o      = (const float*)d_in[2];
    const float* d      = (const float*)d_in[3];
    float*       out    = (float*)d_out;
    float*       cams   = (float*)d_ws;   // size*16 floats (64 KB for size=1000)

    int size = in_sizes[0] / 6;
    long long N = (long long)in_sizes[2] / 3;

    cam_precompute<<<(size + 255) / 256, 256, 0, stream>>>(params, cams, size);

    int blocks = (int)((N + 1023) / 1024);
    cam_apply<<<blocks, 256, 0, stream>>>(idx, o, d, (const f32x4*)cams,
                                          out, N);
}